// Round 1
// baseline (3100.000 us; speedup 1.0000x reference)
//
#include <hip/hip_runtime.h>
#include <math.h>

#define NUM_B 4
#define NUM_N 20000
#define NUM_E 100000
#define DIM 128
#define NH 8
#define NHD 16
#define BN (NUM_B * NUM_N)

__device__ inline void atomicMaxFloat(float* addr, float val) {
  if (val >= 0.0f) {
    atomicMax((int*)addr, __float_as_int(val));
  } else {
    atomicMin((unsigned int*)addr, __float_as_uint(val));
  }
}

// ---------------- init: m = -inf, den = 0, agg(=out) = 0 ----------------
__global__ __launch_bounds__(256) void k_init(float* __restrict__ m,
                                              float* __restrict__ den,
                                              float* __restrict__ agg) {
  int64_t stride = (int64_t)gridDim.x * blockDim.x;
  for (int64_t i = (int64_t)blockIdx.x * blockDim.x + threadIdx.x;
       i < (int64_t)BN * DIM; i += stride) {
    agg[i] = 0.0f;
    if (i < (int64_t)BN * NH) { m[i] = -INFINITY; den[i] = 0.0f; }
  }
}

// ------------- prep: Aq = Wq*attn_q (128x8), Ak = Wk*attn_k, biases ------
__global__ __launch_bounds__(256) void k_prep(
    const float* __restrict__ Wq, const float* __restrict__ bq,
    const float* __restrict__ Wk, const float* __restrict__ bk,
    const float* __restrict__ attn,
    float* __restrict__ Aq, float* __restrict__ Ak, float* __restrict__ cvec) {
  int t = threadIdx.x;
  for (int idx = t; idx < DIM * NH; idx += blockDim.x) {
    int i = idx >> 3, h = idx & 7;
    float sq = 0.f, sk = 0.f;
    for (int d = 0; d < NHD; ++d) {
      sq += Wq[i * DIM + h * NHD + d] * attn[h * 2 * NHD + d];
      sk += Wk[i * DIM + h * NHD + d] * attn[h * 2 * NHD + NHD + d];
    }
    Aq[idx] = sq;
    Ak[idx] = sk;
  }
  if (t < NH) {
    float cq = 0.f, ck = 0.f;
    for (int d = 0; d < NHD; ++d) {
      cq += bq[t * NHD + d] * attn[t * 2 * NHD + d];
      ck += bk[t * NHD + d] * attn[t * 2 * NHD + NHD + d];
    }
    cvec[t] = cq;
    cvec[NH + t] = ck;
  }
}

// ------------- proj: V = X@Wv + bv ; aq = X@Aq + cq ; ak = X@Ak + ck -----
// 16 nodes per 256-thread block; each thread accumulates 8 output rows for
// one column, so each Wv element load feeds 8 FMAs.
__global__ __launch_bounds__(256) void k_proj(
    const float* __restrict__ X, const float* __restrict__ Wv,
    const float* __restrict__ bv, const float* __restrict__ Aq,
    const float* __restrict__ Ak, const float* __restrict__ cvec,
    float* __restrict__ aq, float* __restrict__ ak, float* __restrict__ V) {
  __shared__ float xs[16][DIM];
  int t = threadIdx.x;
  int node0 = blockIdx.x * 16;

  const float4* Xv = (const float4*)(X + (int64_t)node0 * DIM);
  float4* xsv = (float4*)&xs[0][0];
  for (int k = t; k < 16 * DIM / 4; k += 256) xsv[k] = Xv[k];
  __syncthreads();

  int j = t & 127, g = t >> 7;
  float acc[8] = {0.f, 0.f, 0.f, 0.f, 0.f, 0.f, 0.f, 0.f};
  for (int i = 0; i < DIM; ++i) {
    float w = Wv[i * DIM + j];
#pragma unroll
    for (int r = 0; r < 8; ++r) acc[r] += xs[g * 8 + r][i] * w;
  }
  float bvj = bv[j];
#pragma unroll
  for (int r = 0; r < 8; ++r)
    V[(int64_t)(node0 + g * 8 + r) * DIM + j] = acc[r] + bvj;

  // aq/ak: 16 tasks per node (8 heads x {q,k}), one per thread
  int node = t >> 4, k2 = t & 15, h = k2 & 7;
  const float* __restrict__ A = (k2 < 8) ? Aq : Ak;
  float s = cvec[k2];
  for (int i = 0; i < DIM; ++i) s += xs[node][i] * A[i * NH + h];
  if (k2 < 8) aq[(node0 + node) * NH + h] = s;
  else        ak[(node0 + node) * NH + h] = s;
}

// ------------- edge pass 1: per-target per-head max of leaky_relu score --
__global__ __launch_bounds__(256) void k_edge_max(
    const int* __restrict__ eidx, const float* __restrict__ aq,
    const float* __restrict__ ak, float* __restrict__ m) {
  int gid = blockIdx.x * 256 + threadIdx.x;
  if (gid >= NUM_B * NUM_E * NH) return;
  int h = gid & 7;
  int eg = gid >> 3;
  int b = eg / NUM_E, e = eg - b * NUM_E;
  int src = eidx[b * 2 * NUM_E + e];
  int tgt = eidx[b * 2 * NUM_E + NUM_E + e];
  int sf = b * NUM_N + src, seg = b * NUM_N + tgt;
  float s = aq[seg * NH + h] + ak[sf * NH + h];
  s = s > 0.f ? s : 0.2f * s;
  atomicMaxFloat(&m[seg * NH + h], s);
}

// ------------- edge pass 2: ex=exp(s-m); den += ex; agg += ex*V[src] -----
__global__ __launch_bounds__(256) void k_edge_scatter(
    const int* __restrict__ eidx, const float* __restrict__ aq,
    const float* __restrict__ ak, const float* __restrict__ m,
    const float* __restrict__ V, float* __restrict__ den,
    float* __restrict__ agg) {
  int gid = blockIdx.x * 256 + threadIdx.x;
  if (gid >= NUM_B * NUM_E * NH) return;
  int h = gid & 7;
  int eg = gid >> 3;
  int b = eg / NUM_E, e = eg - b * NUM_E;
  int src = eidx[b * 2 * NUM_E + e];
  int tgt = eidx[b * 2 * NUM_E + NUM_E + e];
  int sf = b * NUM_N + src, seg = b * NUM_N + tgt;
  float s = aq[seg * NH + h] + ak[sf * NH + h];
  s = s > 0.f ? s : 0.2f * s;
  float ex = expf(s - m[seg * NH + h]);
  atomicAdd(&den[seg * NH + h], ex);
  const float* vs = V + (int64_t)sf * DIM + h * NHD;
  float* ag = agg + (int64_t)seg * DIM + h * NHD;
#pragma unroll
  for (int d = 0; d < NHD; ++d) atomicAdd(&ag[d], ex * vs[d]);
}

// ------------- epilogue: out = LN(agg/den @ Wo + bo + X) * gamma + beta --
__global__ __launch_bounds__(256) void k_out(
    const float* __restrict__ X, const float* __restrict__ Wo,
    const float* __restrict__ bo, const float* __restrict__ gamma,
    const float* __restrict__ beta, const float* __restrict__ den,
    float* __restrict__ out) {
  __shared__ float as[16][DIM];
  __shared__ float ys[16][DIM];
  __shared__ float dinv[16][NH];
  int t = threadIdx.x;
  int node0 = blockIdx.x * 16;

  if (t < 16 * NH) {
    float d = den[node0 * NH + t];
    dinv[t >> 3][t & 7] = d > 0.f ? 1.0f / d : 0.0f;  // empty segment -> 0
  }
  __syncthreads();

  for (int k = t; k < 16 * DIM; k += 256) {
    int n = k >> 7, i = k & 127;
    as[n][i] = out[(int64_t)(node0 + n) * DIM + i] * dinv[n][i >> 4];
  }
  __syncthreads();

  int j = t & 127, g = t >> 7;
  float acc[8] = {0.f, 0.f, 0.f, 0.f, 0.f, 0.f, 0.f, 0.f};
  for (int i = 0; i < DIM; ++i) {
    float w = Wo[i * DIM + j];
#pragma unroll
    for (int r = 0; r < 8; ++r) acc[r] += as[g * 8 + r][i] * w;
  }
  float boj = bo[j];
#pragma unroll
  for (int r = 0; r < 8; ++r) {
    int n = g * 8 + r;
    ys[n][j] = acc[r] + boj + X[(int64_t)(node0 + n) * DIM + j];
  }
  __syncthreads();

  // LayerNorm: 16 threads per node
  int node = t >> 4, k2 = t & 15;
  float s1 = 0.f, s2 = 0.f;
  for (int q = k2; q < DIM; q += 16) {
    float v = ys[node][q];
    s1 += v;
    s2 += v * v;
  }
#pragma unroll
  for (int off = 1; off < 16; off <<= 1) {
    s1 += __shfl_xor(s1, off);
    s2 += __shfl_xor(s2, off);
  }
  float mu = s1 * (1.0f / DIM);
  float var = s2 * (1.0f / DIM) - mu * mu;
  float rs = rsqrtf(var + 1e-5f);
  for (int q = k2; q < DIM; q += 16) {
    out[(int64_t)(node0 + node) * DIM + q] =
        (ys[node][q] - mu) * rs * gamma[q] + beta[q];
  }
}

extern "C" void kernel_launch(void* const* d_in, const int* in_sizes, int n_in,
                              void* d_out, int out_size, void* d_ws,
                              size_t ws_size, hipStream_t stream) {
  const float* X     = (const float*)d_in[0];
  const int*   eidx  = (const int*)d_in[1];
  const float* Wq    = (const float*)d_in[2];
  const float* bq    = (const float*)d_in[3];
  const float* Wk    = (const float*)d_in[4];
  const float* bk    = (const float*)d_in[5];
  const float* Wv    = (const float*)d_in[6];
  const float* bv    = (const float*)d_in[7];
  const float* attn  = (const float*)d_in[8];
  const float* Wo    = (const float*)d_in[9];
  const float* bo    = (const float*)d_in[10];
  const float* gamma = (const float*)d_in[11];
  const float* beta  = (const float*)d_in[12];
  float* out = (float*)d_out;

  float* ws   = (float*)d_ws;
  float* Aq   = ws;                    // 1024
  float* Ak   = ws + 1024;             // 1024
  float* cvec = ws + 2048;             // 16
  float* aqv  = ws + 2064;             // BN*NH = 640000
  float* akv  = aqv + (int64_t)BN * NH;
  float* m    = akv + (int64_t)BN * NH;
  float* den  = m + (int64_t)BN * NH;
  float* V    = den + (int64_t)BN * NH;  // BN*DIM = 10.24M -> total ~51.2 MB

  k_init<<<2048, 256, 0, stream>>>(m, den, out);
  k_prep<<<1, 256, 0, stream>>>(Wq, bq, Wk, bk, attn, Aq, Ak, cvec);
  k_proj<<<BN / 16, 256, 0, stream>>>(X, Wv, bv, Aq, Ak, cvec, aqv, akv, V);
  int eth = NUM_B * NUM_E * NH;
  k_edge_max<<<(eth + 255) / 256, 256, 0, stream>>>(eidx, aqv, akv, m);
  k_edge_scatter<<<(eth + 255) / 256, 256, 0, stream>>>(eidx, aqv, akv, m, V,
                                                        den, out);
  k_out<<<BN / 16, 256, 0, stream>>>(X, Wo, bo, gamma, beta, den, out);
}

// Round 2
// 288.452 us; speedup vs baseline: 10.7470x; 10.7470x over previous
//
#include <hip/hip_runtime.h>
#include <math.h>

#define NUM_B 4
#define NUM_N 20000
#define NUM_E 100000
#define DIM 128
#define NH 8
#define NHD 16
#define BN (NUM_B * NUM_N)
#define NB ((BN + 255) / 256)  // 313 scan blocks

// ------------- prep: Aq = Wq*attn_q (128x8), Ak = Wk*attn_k, biases ------
__global__ __launch_bounds__(256) void k_prep(
    const float* __restrict__ Wq, const float* __restrict__ bq,
    const float* __restrict__ Wk, const float* __restrict__ bk,
    const float* __restrict__ attn,
    float* __restrict__ Aq, float* __restrict__ Ak, float* __restrict__ cvec) {
  int t = threadIdx.x;
  for (int idx = t; idx < DIM * NH; idx += blockDim.x) {
    int i = idx >> 3, h = idx & 7;
    float sq = 0.f, sk = 0.f;
    for (int d = 0; d < NHD; ++d) {
      sq += Wq[i * DIM + h * NHD + d] * attn[h * 2 * NHD + d];
      sk += Wk[i * DIM + h * NHD + d] * attn[h * 2 * NHD + NHD + d];
    }
    Aq[idx] = sq;
    Ak[idx] = sk;
  }
  if (t < NH) {
    float cq = 0.f, ck = 0.f;
    for (int d = 0; d < NHD; ++d) {
      cq += bq[t * NHD + d] * attn[t * 2 * NHD + d];
      ck += bk[t * NHD + d] * attn[t * 2 * NHD + NHD + d];
    }
    cvec[t] = cq;
    cvec[NH + t] = ck;
  }
}

// ------------- proj: V = X@Wv + bv ; aq = X@Aq + cq ; ak = X@Ak + ck -----
__global__ __launch_bounds__(256) void k_proj(
    const float* __restrict__ X, const float* __restrict__ Wv,
    const float* __restrict__ bv, const float* __restrict__ Aq,
    const float* __restrict__ Ak, const float* __restrict__ cvec,
    float* __restrict__ aq, float* __restrict__ ak, float* __restrict__ V) {
  __shared__ float xs[16][DIM];
  int t = threadIdx.x;
  int node0 = blockIdx.x * 16;

  const float4* Xv = (const float4*)(X + (int64_t)node0 * DIM);
  float4* xsv = (float4*)&xs[0][0];
  for (int k = t; k < 16 * DIM / 4; k += 256) xsv[k] = Xv[k];
  __syncthreads();

  int j = t & 127, g = t >> 7;
  float acc[8] = {0.f, 0.f, 0.f, 0.f, 0.f, 0.f, 0.f, 0.f};
  for (int i = 0; i < DIM; ++i) {
    float w = Wv[i * DIM + j];
#pragma unroll
    for (int r = 0; r < 8; ++r) acc[r] += xs[g * 8 + r][i] * w;
  }
  float bvj = bv[j];
#pragma unroll
  for (int r = 0; r < 8; ++r)
    V[(int64_t)(node0 + g * 8 + r) * DIM + j] = acc[r] + bvj;

  int node = t >> 4, k2 = t & 15, h = k2 & 7;
  const float* __restrict__ A = (k2 < 8) ? Aq : Ak;
  float s = cvec[k2];
  for (int i = 0; i < DIM; ++i) s += xs[node][i] * A[i * NH + h];
  if (k2 < 8) aq[(node0 + node) * NH + h] = s;
  else        ak[(node0 + node) * NH + h] = s;
}

// ------------- CSR build: histogram over targets ------------------------
__global__ __launch_bounds__(256) void k_hist(const int* __restrict__ eidx,
                                              int* __restrict__ counts) {
  int gid = blockIdx.x * 256 + threadIdx.x;
  if (gid >= NUM_B * NUM_E) return;
  int b = gid / NUM_E, e = gid - b * NUM_E;
  int tgt = eidx[b * 2 * NUM_E + NUM_E + e];
  atomicAdd(&counts[b * NUM_N + tgt], 1);
}

// exclusive scan, 3 phases
__global__ __launch_bounds__(256) void k_scan1(const int* __restrict__ counts,
                                               int* __restrict__ starts,
                                               int* __restrict__ bsums) {
  __shared__ int sh[256];
  int i = blockIdx.x * 256 + threadIdx.x;
  int v = (i < BN) ? counts[i] : 0;
  sh[threadIdx.x] = v;
  __syncthreads();
  for (int off = 1; off < 256; off <<= 1) {
    int t = (threadIdx.x >= off) ? sh[threadIdx.x - off] : 0;
    __syncthreads();
    sh[threadIdx.x] += t;
    __syncthreads();
  }
  if (i < BN) starts[i] = sh[threadIdx.x] - v;  // exclusive within block
  if (threadIdx.x == 255) bsums[blockIdx.x] = sh[255];
}

__global__ __launch_bounds__(512) void k_scan2(int* __restrict__ bsums) {
  __shared__ int sh[512];
  int t = threadIdx.x;
  int v = (t < NB) ? bsums[t] : 0;
  sh[t] = v;
  __syncthreads();
  for (int off = 1; off < 512; off <<= 1) {
    int u = (t >= off) ? sh[t - off] : 0;
    __syncthreads();
    sh[t] += u;
    __syncthreads();
  }
  if (t < NB) bsums[t] = sh[t] - v;  // exclusive
}

__global__ __launch_bounds__(256) void k_scan3(int* __restrict__ starts,
                                               const int* __restrict__ bsums,
                                               int* __restrict__ cursor) {
  int i = blockIdx.x * 256 + threadIdx.x;
  if (i < BN) {
    int s = starts[i] + bsums[blockIdx.x];
    starts[i] = s;
    cursor[i] = s;
  }
}

// scatter src ids into CSR order (order within a segment is arbitrary)
__global__ __launch_bounds__(256) void k_scatter(const int* __restrict__ eidx,
                                                 int* __restrict__ cursor,
                                                 int* __restrict__ sorted_src) {
  int gid = blockIdx.x * 256 + threadIdx.x;
  if (gid >= NUM_B * NUM_E) return;
  int b = gid / NUM_E, e = gid - b * NUM_E;
  int src = eidx[b * 2 * NUM_E + e];
  int tgt = eidx[b * 2 * NUM_E + NUM_E + e];
  int pos = atomicAdd(&cursor[b * NUM_N + tgt], 1);
  sorted_src[pos] = b * NUM_N + src;
}

// ------------- gather: one wave per target node, no atomics -------------
// lane owns output dims j=lane and j+64 -> heads h1=lane>>4, h2=h1+4.
// After scatter, cursor[node] == end offset of node's edge list.
__global__ __launch_bounds__(256) void k_gather(
    const int* __restrict__ sorted_src, const int* __restrict__ starts,
    const int* __restrict__ ends, const float* __restrict__ aq,
    const float* __restrict__ ak, const float* __restrict__ V,
    float* __restrict__ out) {
  int tid = threadIdx.x;
  int node = blockIdx.x * 4 + (tid >> 6);
  if (node >= BN) return;
  int lane = tid & 63;
  int h1 = lane >> 4, h2 = h1 + 4;
  int s0 = starts[node], s1 = ends[node];
  float aqv1 = aq[node * NH + h1], aqv2 = aq[node * NH + h2];

  // pass 1: per-head max (broadcast loads; avg degree ~5)
  float m1 = -INFINITY, m2 = -INFINITY;
  for (int p = s0; p < s1; ++p) {
    int sf = sorted_src[p];
    float t1 = aqv1 + ak[sf * NH + h1];
    float t2 = aqv2 + ak[sf * NH + h2];
    t1 = t1 > 0.f ? t1 : 0.2f * t1;
    t2 = t2 > 0.f ? t2 : 0.2f * t2;
    m1 = fmaxf(m1, t1);
    m2 = fmaxf(m2, t2);
  }

  // pass 2: accumulate exp-weighted V rows (one coalesced 512B row / edge)
  float acc1 = 0.f, acc2 = 0.f, den1 = 0.f, den2 = 0.f;
  for (int p = s0; p < s1; ++p) {
    int sf = sorted_src[p];
    float t1 = aqv1 + ak[sf * NH + h1];
    float t2 = aqv2 + ak[sf * NH + h2];
    t1 = t1 > 0.f ? t1 : 0.2f * t1;
    t2 = t2 > 0.f ? t2 : 0.2f * t2;
    float e1 = expf(t1 - m1), e2 = expf(t2 - m2);
    const float* vr = V + (int64_t)sf * DIM;
    acc1 += e1 * vr[lane];
    acc2 += e2 * vr[lane + 64];
    den1 += e1;
    den2 += e2;
  }
  float o1 = den1 > 0.f ? acc1 / den1 : 0.f;
  float o2 = den2 > 0.f ? acc2 / den2 : 0.f;
  out[(int64_t)node * DIM + lane] = o1;
  out[(int64_t)node * DIM + lane + 64] = o2;
}

// ------------- epilogue: out = LN(agg @ Wo + bo + X) * gamma + beta -----
__global__ __launch_bounds__(256) void k_out(
    const float* __restrict__ X, const float* __restrict__ Wo,
    const float* __restrict__ bo, const float* __restrict__ gamma,
    const float* __restrict__ beta, float* __restrict__ out) {
  __shared__ float as[16][DIM];
  __shared__ float ys[16][DIM];
  int t = threadIdx.x;
  int node0 = blockIdx.x * 16;

  for (int k = t; k < 16 * DIM; k += 256) {
    int n = k >> 7, i = k & 127;
    as[n][i] = out[(int64_t)(node0 + n) * DIM + i];
  }
  __syncthreads();

  int j = t & 127, g = t >> 7;
  float acc[8] = {0.f, 0.f, 0.f, 0.f, 0.f, 0.f, 0.f, 0.f};
  for (int i = 0; i < DIM; ++i) {
    float w = Wo[i * DIM + j];
#pragma unroll
    for (int r = 0; r < 8; ++r) acc[r] += as[g * 8 + r][i] * w;
  }
  float boj = bo[j];
#pragma unroll
  for (int r = 0; r < 8; ++r) {
    int n = g * 8 + r;
    ys[n][j] = acc[r] + boj + X[(int64_t)(node0 + n) * DIM + j];
  }
  __syncthreads();

  int node = t >> 4, k2 = t & 15;
  float s1 = 0.f, s2 = 0.f;
  for (int q = k2; q < DIM; q += 16) {
    float v = ys[node][q];
    s1 += v;
    s2 += v * v;
  }
#pragma unroll
  for (int off = 1; off < 16; off <<= 1) {
    s1 += __shfl_xor(s1, off);
    s2 += __shfl_xor(s2, off);
  }
  float mu = s1 * (1.0f / DIM);
  float var = s2 * (1.0f / DIM) - mu * mu;
  float rs = rsqrtf(var + 1e-5f);
  for (int q = k2; q < DIM; q += 16) {
    out[(int64_t)(node0 + node) * DIM + q] =
        (ys[node][q] - mu) * rs * gamma[q] + beta[q];
  }
}

extern "C" void kernel_launch(void* const* d_in, const int* in_sizes, int n_in,
                              void* d_out, int out_size, void* d_ws,
                              size_t ws_size, hipStream_t stream) {
  const float* X     = (const float*)d_in[0];
  const int*   eidx  = (const int*)d_in[1];
  const float* Wq    = (const float*)d_in[2];
  const float* bq    = (const float*)d_in[3];
  const float* Wk    = (const float*)d_in[4];
  const float* bk    = (const float*)d_in[5];
  const float* Wv    = (const float*)d_in[6];
  const float* bv    = (const float*)d_in[7];
  const float* attn  = (const float*)d_in[8];
  const float* Wo    = (const float*)d_in[9];
  const float* bo    = (const float*)d_in[10];
  const float* gamma = (const float*)d_in[11];
  const float* beta  = (const float*)d_in[12];
  float* out = (float*)d_out;

  float* ws   = (float*)d_ws;
  float* Aq   = ws;                      // 1024
  float* Ak   = ws + 1024;               // 1024
  float* cvec = ws + 2048;               // 16
  float* aqv  = ws + 2064;               // BN*NH
  float* akv  = aqv + (int64_t)BN * NH;  // BN*NH
  float* V    = akv + (int64_t)BN * NH;  // BN*DIM
  int* counts     = (int*)(V + (int64_t)BN * DIM);  // BN
  int* starts     = counts + BN;                    // BN
  int* cursor     = starts + BN;                    // BN
  int* bsums      = cursor + BN;                    // NB (<=320)
  int* sorted_src = bsums + 320;                    // B*E

  hipMemsetAsync(counts, 0, (size_t)BN * sizeof(int), stream);
  k_prep<<<1, 256, 0, stream>>>(Wq, bq, Wk, bk, attn, Aq, Ak, cvec);
  k_proj<<<BN / 16, 256, 0, stream>>>(X, Wv, bv, Aq, Ak, cvec, aqv, akv, V);

  int ne = NUM_B * NUM_E;
  k_hist<<<(ne + 255) / 256, 256, 0, stream>>>(eidx, counts);
  k_scan1<<<NB, 256, 0, stream>>>(counts, starts, bsums);
  k_scan2<<<1, 512, 0, stream>>>(bsums);
  k_scan3<<<NB, 256, 0, stream>>>(starts, bsums, cursor);
  k_scatter<<<(ne + 255) / 256, 256, 0, stream>>>(eidx, cursor, sorted_src);

  k_gather<<<BN / 4, 256, 0, stream>>>(sorted_src, starts, cursor, aqv, akv, V,
                                       out);
  k_out<<<BN / 16, 256, 0, stream>>>(X, Wo, bo, gamma, beta, out);
}

// Round 3
// 216.285 us; speedup vs baseline: 14.3329x; 1.3337x over previous
//
#include <hip/hip_runtime.h>
#include <math.h>

#define NUM_B 4
#define NUM_N 20000
#define NUM_E 100000
#define DIM 128
#define NH 8
#define NHD 16
#define BN (NUM_B * NUM_N)
#define NB ((BN + 255) / 256)  // 313 scan blocks
#define XPAD 132               // padded LDS row stride (floats)

// ------------- prep: Aq = Wq*attn_q (128x8), Ak = Wk*attn_k, biases ------
__global__ __launch_bounds__(256) void k_prep(
    const float* __restrict__ Wq, const float* __restrict__ bq,
    const float* __restrict__ Wk, const float* __restrict__ bk,
    const float* __restrict__ attn,
    float* __restrict__ Aq, float* __restrict__ Ak, float* __restrict__ cvec) {
  int t = threadIdx.x;
  for (int idx = t; idx < DIM * NH; idx += blockDim.x) {
    int i = idx >> 3, h = idx & 7;
    float sq = 0.f, sk = 0.f;
    for (int d = 0; d < NHD; ++d) {
      sq += Wq[i * DIM + h * NHD + d] * attn[h * 2 * NHD + d];
      sk += Wk[i * DIM + h * NHD + d] * attn[h * 2 * NHD + NHD + d];
    }
    Aq[idx] = sq;
    Ak[idx] = sk;
  }
  if (t < NH) {
    float cq = 0.f, ck = 0.f;
    for (int d = 0; d < NHD; ++d) {
      cq += bq[t * NHD + d] * attn[t * 2 * NHD + d];
      ck += bk[t * NHD + d] * attn[t * 2 * NHD + NHD + d];
    }
    cvec[t] = cq;
    cvec[NH + t] = ck;
  }
}

// ------------- proj: V = X@Wv + bv ; aq = X@Aq + cq ; ak = X@Ak + ck -----
// 64 nodes / block; thread owns 8 rows x 4 cols -> 32 FMA per (8 LDS + 1
// float4) loads.
__global__ __launch_bounds__(256) void k_proj(
    const float* __restrict__ X, const float* __restrict__ Wv,
    const float* __restrict__ bv, const float* __restrict__ Aq,
    const float* __restrict__ Ak, const float* __restrict__ cvec,
    float* __restrict__ aq, float* __restrict__ ak, float* __restrict__ V) {
  __shared__ float xs[64][XPAD];
  __shared__ float AqS[DIM * NH];
  __shared__ float AkS[DIM * NH];
  int t = threadIdx.x;
  int node0 = blockIdx.x * 64;

  const float4* Xv = (const float4*)(X + (int64_t)node0 * DIM);
  for (int k = t; k < 64 * DIM / 4; k += 256) {
    int n = k >> 5, c = k & 31;
    ((float4*)&xs[n][0])[c] = Xv[k];
  }
  for (int k = t; k < DIM * NH; k += 256) {
    AqS[k] = Aq[k];
    AkS[k] = Ak[k];
  }
  __syncthreads();

  int c = t & 31, g = t >> 5;  // cols 4c..4c+3, rows 8g..8g+7
  float acc[8][4];
#pragma unroll
  for (int r = 0; r < 8; ++r)
#pragma unroll
    for (int q = 0; q < 4; ++q) acc[r][q] = 0.f;

  const float4* Wv4 = (const float4*)Wv;
  for (int i = 0; i < DIM; ++i) {
    float4 w = Wv4[i * 32 + c];
#pragma unroll
    for (int r = 0; r < 8; ++r) {
      float x = xs[g * 8 + r][i];
      acc[r][0] += x * w.x;
      acc[r][1] += x * w.y;
      acc[r][2] += x * w.z;
      acc[r][3] += x * w.w;
    }
  }
  float4 bv4 = ((const float4*)bv)[c];
  float4* V4 = (float4*)V;
#pragma unroll
  for (int r = 0; r < 8; ++r) {
    float4 o;
    o.x = acc[r][0] + bv4.x;
    o.y = acc[r][1] + bv4.y;
    o.z = acc[r][2] + bv4.z;
    o.w = acc[r][3] + bv4.w;
    V4[(int64_t)(node0 + g * 8 + r) * 32 + c] = o;
  }

  // aq/ak: 64 nodes x 16 tasks, 4 tasks per thread
  for (int task = t; task < 64 * 16; task += 256) {
    int node = task >> 4, k2 = task & 15, h = k2 & 7;
    const float* As = (k2 < 8) ? AqS : AkS;
    float s = cvec[k2];
    for (int i = 0; i < DIM; ++i) s += xs[node][i] * As[i * NH + h];
    if (k2 < 8) aq[(node0 + node) * NH + h] = s;
    else        ak[(node0 + node) * NH + h] = s;
  }
}

// ------------- CSR build ------------------------------------------------
__global__ __launch_bounds__(256) void k_hist(const int* __restrict__ eidx,
                                              int* __restrict__ counts) {
  int gid = blockIdx.x * 256 + threadIdx.x;
  if (gid >= NUM_B * NUM_E) return;
  int b = gid / NUM_E, e = gid - b * NUM_E;
  int tgt = eidx[b * 2 * NUM_E + NUM_E + e];
  atomicAdd(&counts[b * NUM_N + tgt], 1);
}

__global__ __launch_bounds__(256) void k_scan1(const int* __restrict__ counts,
                                               int* __restrict__ starts,
                                               int* __restrict__ bsums) {
  __shared__ int sh[256];
  int i = blockIdx.x * 256 + threadIdx.x;
  int v = (i < BN) ? counts[i] : 0;
  sh[threadIdx.x] = v;
  __syncthreads();
  for (int off = 1; off < 256; off <<= 1) {
    int t = (threadIdx.x >= off) ? sh[threadIdx.x - off] : 0;
    __syncthreads();
    sh[threadIdx.x] += t;
    __syncthreads();
  }
  if (i < BN) starts[i] = sh[threadIdx.x] - v;
  if (threadIdx.x == 255) bsums[blockIdx.x] = sh[255];
}

__global__ __launch_bounds__(512) void k_scan2(int* __restrict__ bsums) {
  __shared__ int sh[512];
  int t = threadIdx.x;
  int v = (t < NB) ? bsums[t] : 0;
  sh[t] = v;
  __syncthreads();
  for (int off = 1; off < 512; off <<= 1) {
    int u = (t >= off) ? sh[t - off] : 0;
    __syncthreads();
    sh[t] += u;
    __syncthreads();
  }
  if (t < NB) bsums[t] = sh[t] - v;
}

__global__ __launch_bounds__(256) void k_scan3(int* __restrict__ starts,
                                               const int* __restrict__ bsums) {
  int i = blockIdx.x * 256 + threadIdx.x;
  if (i < BN) starts[i] += bsums[blockIdx.x];
}

// scatter src ids into CSR order; bumps starts so afterwards starts[n]=end(n)
__global__ __launch_bounds__(256) void k_scatter(const int* __restrict__ eidx,
                                                 int* __restrict__ starts,
                                                 int* __restrict__ sorted_src) {
  int gid = blockIdx.x * 256 + threadIdx.x;
  if (gid >= NUM_B * NUM_E) return;
  int b = gid / NUM_E, e = gid - b * NUM_E;
  int src = eidx[b * 2 * NUM_E + e];
  int tgt = eidx[b * 2 * NUM_E + NUM_E + e];
  int pos = atomicAdd(&starts[b * NUM_N + tgt], 1);
  sorted_src[pos] = b * NUM_N + src;
}

// ------------- gather: one wave per node, single pass, no atomics -------
// lane owns dims 2*lane, 2*lane+1 -> head h = lane>>3. exp without max
// subtraction (w = ex/den is shift-invariant; |s| <~ 16 here, fp32-safe).
__global__ __launch_bounds__(256) void k_gather(
    const int* __restrict__ sorted_src, const int* __restrict__ ends,
    const int* __restrict__ counts, const float* __restrict__ aq,
    const float* __restrict__ ak, const float* __restrict__ V,
    float* __restrict__ out) {
  int tid = threadIdx.x;
  int node = blockIdx.x * 4 + (tid >> 6);
  int lane = tid & 63;
  int h = lane >> 3;
  int s1 = ends[node];
  int s0 = s1 - counts[node];
  float aqh = aq[node * NH + h];

  float accx = 0.f, accy = 0.f, den = 0.f;
  for (int p = s0; p < s1; ++p) {
    int sf = sorted_src[p];
    float s = aqh + ak[sf * NH + h];
    s = s > 0.f ? s : 0.2f * s;
    float e = __expf(s);
    float2 v = *(const float2*)(V + (int64_t)sf * DIM + 2 * lane);
    accx += e * v.x;
    accy += e * v.y;
    den += e;
  }
  float inv = den > 0.f ? 1.0f / den : 0.f;
  float2 o;
  o.x = accx * inv;
  o.y = accy * inv;
  *(float2*)(out + (int64_t)node * DIM + 2 * lane) = o;
}

// ------------- epilogue: out = LN(agg @ Wo + bo + X) * gamma + beta -----
// 64 nodes / block, 8x4 register tile, LN fully in registers.
__global__ __launch_bounds__(256) void k_out(
    const float* __restrict__ X, const float* __restrict__ Wo,
    const float* __restrict__ bo, const float* __restrict__ gamma,
    const float* __restrict__ beta, float* __restrict__ out) {
  __shared__ float as[64][XPAD];
  int t = threadIdx.x;
  int node0 = blockIdx.x * 64;

  const float4* Av = (const float4*)(out + (int64_t)node0 * DIM);
  for (int k = t; k < 64 * DIM / 4; k += 256) {
    int n = k >> 5, c = k & 31;
    ((float4*)&as[n][0])[c] = Av[k];
  }
  __syncthreads();

  int c = t & 31, g = t >> 5;
  float acc[8][4];
#pragma unroll
  for (int r = 0; r < 8; ++r)
#pragma unroll
    for (int q = 0; q < 4; ++q) acc[r][q] = 0.f;

  const float4* Wo4 = (const float4*)Wo;
  for (int i = 0; i < DIM; ++i) {
    float4 w = Wo4[i * 32 + c];
#pragma unroll
    for (int r = 0; r < 8; ++r) {
      float a = as[g * 8 + r][i];
      acc[r][0] += a * w.x;
      acc[r][1] += a * w.y;
      acc[r][2] += a * w.z;
      acc[r][3] += a * w.w;
    }
  }

  float4 bo4 = ((const float4*)bo)[c];
  const float4* X4 = (const float4*)X;
  float s1v[8], s2v[8];
#pragma unroll
  for (int r = 0; r < 8; ++r) {
    int row = node0 + g * 8 + r;
    float4 xr = X4[(int64_t)row * 32 + c];
    acc[r][0] += bo4.x + xr.x;
    acc[r][1] += bo4.y + xr.y;
    acc[r][2] += bo4.z + xr.z;
    acc[r][3] += bo4.w + xr.w;
    float s1 = acc[r][0] + acc[r][1] + acc[r][2] + acc[r][3];
    float s2 = acc[r][0] * acc[r][0] + acc[r][1] * acc[r][1] +
               acc[r][2] * acc[r][2] + acc[r][3] * acc[r][3];
    s1v[r] = s1;
    s2v[r] = s2;
  }
  // reduce across the 32 lanes sharing this row group (xor<32 stays in half)
#pragma unroll
  for (int off = 1; off < 32; off <<= 1) {
#pragma unroll
    for (int r = 0; r < 8; ++r) {
      s1v[r] += __shfl_xor(s1v[r], off);
      s2v[r] += __shfl_xor(s2v[r], off);
    }
  }
  float4 gm = ((const float4*)gamma)[c];
  float4 bt = ((const float4*)beta)[c];
  float4* O4 = (float4*)out;
#pragma unroll
  for (int r = 0; r < 8; ++r) {
    float mu = s1v[r] * (1.0f / DIM);
    float var = s2v[r] * (1.0f / DIM) - mu * mu;
    float rs = rsqrtf(var + 1e-5f);
    float4 o;
    o.x = (acc[r][0] - mu) * rs * gm.x + bt.x;
    o.y = (acc[r][1] - mu) * rs * gm.y + bt.y;
    o.z = (acc[r][2] - mu) * rs * gm.z + bt.z;
    o.w = (acc[r][3] - mu) * rs * gm.w + bt.w;
    O4[(int64_t)(node0 + g * 8 + r) * 32 + c] = o;
  }
}

extern "C" void kernel_launch(void* const* d_in, const int* in_sizes, int n_in,
                              void* d_out, int out_size, void* d_ws,
                              size_t ws_size, hipStream_t stream) {
  const float* X     = (const float*)d_in[0];
  const int*   eidx  = (const int*)d_in[1];
  const float* Wq    = (const float*)d_in[2];
  const float* bq    = (const float*)d_in[3];
  const float* Wk    = (const float*)d_in[4];
  const float* bk    = (const float*)d_in[5];
  const float* Wv    = (const float*)d_in[6];
  const float* bv    = (const float*)d_in[7];
  const float* attn  = (const float*)d_in[8];
  const float* Wo    = (const float*)d_in[9];
  const float* bo    = (const float*)d_in[10];
  const float* gamma = (const float*)d_in[11];
  const float* beta  = (const float*)d_in[12];
  float* out = (float*)d_out;

  float* ws   = (float*)d_ws;
  float* Aq   = ws;                      // 1024
  float* Ak   = ws + 1024;               // 1024
  float* cvec = ws + 2048;               // 16
  float* aqv  = ws + 2064;               // BN*NH
  float* akv  = aqv + (int64_t)BN * NH;  // BN*NH
  float* V    = akv + (int64_t)BN * NH;  // BN*DIM
  int* counts     = (int*)(V + (int64_t)BN * DIM);  // BN
  int* starts     = counts + BN;                    // BN
  int* bsums      = starts + BN;                    // NB (<=320)
  int* sorted_src = bsums + 320;                    // B*E

  hipMemsetAsync(counts, 0, (size_t)BN * sizeof(int), stream);
  k_prep<<<1, 256, 0, stream>>>(Wq, bq, Wk, bk, attn, Aq, Ak, cvec);
  k_proj<<<BN / 64, 256, 0, stream>>>(X, Wv, bv, Aq, Ak, cvec, aqv, akv, V);

  int ne = NUM_B * NUM_E;
  k_hist<<<(ne + 255) / 256, 256, 0, stream>>>(eidx, counts);
  k_scan1<<<NB, 256, 0, stream>>>(counts, starts, bsums);
  k_scan2<<<1, 512, 0, stream>>>(bsums);
  k_scan3<<<NB, 256, 0, stream>>>(starts, bsums);
  k_scatter<<<(ne + 255) / 256, 256, 0, stream>>>(eidx, starts, sorted_src);

  k_gather<<<BN / 4, 256, 0, stream>>>(sorted_src, starts, counts, aqv, akv, V,
                                       out);
  k_out<<<BN / 64, 256, 0, stream>>>(X, Wo, bo, gamma, beta, out);
}